// Round 2
// baseline (331.608 us; speedup 1.0000x reference)
//
#include <hip/hip_runtime.h>

// WeightedBCELoss: out[b][s] = labels==0 ? -log(1-pred) : -weight[b]*log(pred)
// BATCH=4096, SENT=8192, fp32 (labels int32).
// Memory-bound elementwise: 402 MB total -> ~64 us floor @ 6.3 TB/s achievable.
//
// R1/R2 theory: the 1-float4-per-thread, 32768-block version was latency/
// dispatch-structure bound: 2.6 TB/s with VALUBusy 15%, Occupancy 68% -> no
// pipe saturated. Fix:
//   * grid-stride, 2048 blocks (256 CU x 8 blocks/CU), 16 float4/thread
//   * 4-deep load batching: 8 independent vector loads in flight per wave
//   * nontemporal stores: output (never re-read) stays out of L2/L3 so the
//     exactly-L3-sized input streams stay resident across bench iterations
//   * fold -ln2 / -w*ln2 into one select + v_log_f32 + v_mul per element
// (R1 run died in container acquisition, not in the kernel; resubmitting.)

#define WBCE_BATCH 4096
#define WBCE_SENT  8192
#define LOG2_VEC_PER_ROW 11                         // SENT/4 = 2048 float4/row
#define N_VEC   (WBCE_BATCH * (WBCE_SENT / 4))      // 8,388,608 float4 groups

#define THREADS 256
#define BLOCKS  2048                                // 256 CUs x 8 blocks/CU
#define STRIDE  (BLOCKS * THREADS)                  // 524,288
#define ITERS   (N_VEC / STRIDE)                    // 16, exact (no tail)
#define BATCHN  4                                   // loads in flight per batch

typedef float f32x4 __attribute__((ext_vector_type(4)));

__global__ __launch_bounds__(THREADS) void WeightedBCELoss_70128226009669_kernel(
    const float4* __restrict__ pred4,
    const int4*  __restrict__ lab4,
    const float* __restrict__ weight,
    float4* __restrict__ out4)
{
    const int tid = blockIdx.x * THREADS + threadIdx.x;
    constexpr float NEG_LN2 = -0.69314718055994530942f;

    for (int u = 0; u < ITERS; u += BATCHN) {
        float4 p[BATCHN];
        int4   l[BATCHN];

        const int base = tid + u * STRIDE;

        // Issue all BATCHN*2 loads before any use: 8 independent vector
        // loads in flight per wave (vs 2 in the round-0 version).
        #pragma unroll
        for (int k = 0; k < BATCHN; ++k) {
            p[k] = pred4[base + k * STRIDE];
            l[k] = lab4[base + k * STRIDE];
        }

        #pragma unroll
        for (int k = 0; k < BATCHN; ++k) {
            const int idx = base + k * STRIDE;

            // Wave-uniform row (2048 vec/row is a multiple of 64, so 64
            // consecutive idx never cross a row boundary) -> scalar path.
            const int row = __builtin_amdgcn_readfirstlane(idx >> LOG2_VEC_PER_ROW);
            const float wn = weight[row] * NEG_LN2;   // -w*ln2, scalar load

            // out = sf * log2(x), sf in {-ln2, -w*ln2}: per element this is
            // 1 sub + 2 cndmask + 1 v_log_f32 + 1 v_mul.
            const float x0 = (l[k].x == 0) ? (1.0f - p[k].x) : p[k].x;
            const float x1 = (l[k].y == 0) ? (1.0f - p[k].y) : p[k].y;
            const float x2 = (l[k].z == 0) ? (1.0f - p[k].z) : p[k].z;
            const float x3 = (l[k].w == 0) ? (1.0f - p[k].w) : p[k].w;

            const float s0 = (l[k].x == 0) ? NEG_LN2 : wn;
            const float s1 = (l[k].y == 0) ? NEG_LN2 : wn;
            const float s2 = (l[k].z == 0) ? NEG_LN2 : wn;
            const float s3 = (l[k].w == 0) ? NEG_LN2 : wn;

            f32x4 o;
            o.x = s0 * __log2f(x0);
            o.y = s1 * __log2f(x1);
            o.z = s2 * __log2f(x2);
            o.w = s3 * __log2f(x3);

            // Streaming store: never re-read; keep it out of L2/L3 so the
            // input streams stay L3-resident across bench iterations.
            __builtin_nontemporal_store(o, (f32x4*)&out4[idx]);
        }
    }
}

extern "C" void kernel_launch(void* const* d_in, const int* in_sizes, int n_in,
                              void* d_out, int out_size, void* d_ws, size_t ws_size,
                              hipStream_t stream) {
    const float4* pred4  = (const float4*)d_in[0];
    const int4*   lab4   = (const int4*)d_in[1];
    const float*  weight = (const float*)d_in[2];
    float4* out4 = (float4*)d_out;

    WeightedBCELoss_70128226009669_kernel<<<BLOCKS, THREADS, 0, stream>>>(
        pred4, lab4, weight, out4);
}

// Round 3
// 308.085 us; speedup vs baseline: 1.0764x; 1.0764x over previous
//
#include <hip/hip_runtime.h>

// WeightedBCELoss: out[b][s] = labels==0 ? -log(1-pred) : -weight[b]*log(pred)
// BATCH=4096, SENT=8192, fp32 (labels int32). 402 MB total traffic.
//
// R3 theory: R0 (1 float4/thread, contiguous sweep) ran 102 us @ 3.9 TB/s
// combined; R2 (grid-stride 8MiB batching + nt stores) REGRESSED to 134 us
// -> the contiguous global sweep matters (DRAM locality), nt stores don't
// help L3 retention (FETCH unchanged). Keep R0's sweep + math, add MLP:
//   * each block owns a contiguous 1024-float4 (16 KiB/array) chunk
//   * each thread does 4 float4 at wave-stride (base + k*256): every load
//     is a perfectly coalesced 1 KiB transaction, 8 loads in flight/wave
//   * 8192 blocks -- plenty for dispatch pipelining, sweep order preserved
//   * block never crosses a row (1024 = row/2) -> weight is a scalar load
//   * plain stores, R0 numerics (-s * __logf(x), absmax 0.0156)

#define WBCE_BATCH 4096
#define WBCE_SENT  8192
#define LOG2_VEC_PER_ROW 11                     // SENT/4 = 2048 float4/row
#define N_VEC   (WBCE_BATCH * (WBCE_SENT / 4))  // 8,388,608 float4 groups

#define THREADS 256
#define PER_THREAD 4
#define VEC_PER_BLOCK (THREADS * PER_THREAD)    // 1024 float4 = half a row
#define BLOCKS (N_VEC / VEC_PER_BLOCK)          // 8192, exact (no tail)

typedef float f32x4 __attribute__((ext_vector_type(4)));

__global__ __launch_bounds__(THREADS) void WeightedBCELoss_70128226009669_kernel(
    const float4* __restrict__ pred4,
    const int4*  __restrict__ lab4,
    const float* __restrict__ weight,
    float4* __restrict__ out4)
{
    // Block-contiguous chunk; thread covers k*256-strided float4s inside it.
    const int base = blockIdx.x * VEC_PER_BLOCK + threadIdx.x;

    // 1024 float4/block, 2048 float4/row -> row is block-uniform.
    const float w = weight[blockIdx.x >> 1];    // scalar (SGPR) load

    float4 p[PER_THREAD];
    int4   l[PER_THREAD];

    // Issue all 8 vector loads before any use: 8 in flight per wave.
    #pragma unroll
    for (int k = 0; k < PER_THREAD; ++k) {
        p[k] = pred4[base + k * THREADS];
        l[k] = lab4[base + k * THREADS];
    }

    #pragma unroll
    for (int k = 0; k < PER_THREAD; ++k) {
        // Select log argument first: ONE log per element (R0 numerics).
        const float x0 = (l[k].x == 0) ? (1.0f - p[k].x) : p[k].x;
        const float x1 = (l[k].y == 0) ? (1.0f - p[k].y) : p[k].y;
        const float x2 = (l[k].z == 0) ? (1.0f - p[k].z) : p[k].z;
        const float x3 = (l[k].w == 0) ? (1.0f - p[k].w) : p[k].w;

        const float s0 = (l[k].x == 0) ? 1.0f : w;
        const float s1 = (l[k].y == 0) ? 1.0f : w;
        const float s2 = (l[k].z == 0) ? 1.0f : w;
        const float s3 = (l[k].w == 0) ? 1.0f : w;

        float4 o;
        o.x = -s0 * __logf(x0);
        o.y = -s1 * __logf(x1);
        o.z = -s2 * __logf(x2);
        o.w = -s3 * __logf(x3);

        out4[base + k * THREADS] = o;
    }
}

extern "C" void kernel_launch(void* const* d_in, const int* in_sizes, int n_in,
                              void* d_out, int out_size, void* d_ws, size_t ws_size,
                              hipStream_t stream) {
    const float4* pred4  = (const float4*)d_in[0];
    const int4*   lab4   = (const int4*)d_in[1];
    const float*  weight = (const float*)d_in[2];
    float4* out4 = (float4*)d_out;

    WeightedBCELoss_70128226009669_kernel<<<BLOCKS, THREADS, 0, stream>>>(
        pred4, lab4, weight, out4);
}